// Round 3
// baseline (313.694 us; speedup 1.0000x reference)
//
#include <hip/hip_runtime.h>
#include <hip/hip_bf16.h>

typedef unsigned short u16;
typedef __attribute__((ext_vector_type(8))) unsigned short u16x8;
typedef __attribute__((ext_vector_type(4))) float f32x4;

#define TPB 128

__device__ __forceinline__ float bf2f(u16 v){
  union { unsigned int u; float f; } x; x.u = ((unsigned int)v) << 16; return x.f;
}
__device__ __forceinline__ u16 f2bf(float f){
  union { float f; unsigned int u; } x; x.f = f;
  unsigned int u = x.u;
  u += 0x7FFFu + ((u >> 16) & 1u);   // round-to-nearest-even
  return (u16)(u >> 16);
}
// dtype-flexible load: isbf ? bf16[idx] : f32[idx]
__device__ __forceinline__ float ld(const void* p, int idx, int isbf){
  return isbf ? bf2f(((const u16*)p)[idx]) : ((const float*)p)[idx];
}

// ---------------- kernel 1: dtype detect + per-species atom lists ------------
// ws layout (ints): ws[0..9]=counts; ws[15]=isbf16 flag; ws[16 + e*1024 + j]=atom list
__global__ void k_classify(const void* __restrict__ nav, int* __restrict__ ws){
  __shared__ int se[1024];
  __shared__ int sf[16];
  __shared__ int sflag;
  const int b = threadIdx.x;  // 1024 threads

  // --- dtype detection on node_attrs ---
  // f32 one-hot: words are only 0x00000000 / 0x3F800000.
  // bf16 one-hot: even-index hot produces word 0x00003F80 (never valid f32 here).
  // First 5120 words are in-bounds under BOTH interpretations.
  const unsigned int* w = (const unsigned int*)nav;
  int found = 0;
  for (int i = b; i < 5120; i += 1024) found |= (w[i] == 0x00003F80u);
  unsigned long long m = __ballot(found);
  if ((b & 63) == 0) sf[b >> 6] = (m != 0ULL);
  __syncthreads();
  if (b == 0){ int f = 0; for (int i = 0; i < 16; i++) f |= sf[i]; sflag = f; ws[15] = f; }
  __syncthreads();
  const int isbf = sflag;

  // --- species of atom b ---
  int e = 0;
  #pragma unroll
  for (int j = 0; j < 10; j++){
    if (ld(nav, b*10 + j, isbf) > 0.5f) e = j;
  }
  se[b] = e;
  __syncthreads();
  if (b < 10){
    int cnt = 0;
    int* lst = ws + 16 + b*1024;
    for (int i = 0; i < 1024; i++){
      if (se[i] == b) lst[cnt++] = i;
    }
    ws[b] = cnt;
  }
}

// ---------------- kernel 2: one block per (species e, channel c) -------------
__global__ __launch_bounds__(TPB) void k_contract(
    const void* __restrict__ a_i,
    const void* __restrict__ U3_0, const void* __restrict__ U2_0, const void* __restrict__ U1_0,
    const void* __restrict__ W3_0, const void* __restrict__ W2_0, const void* __restrict__ W1_0,
    const void* __restrict__ U3_1, const void* __restrict__ U2_1, const void* __restrict__ U1_1,
    const void* __restrict__ W3_1, const void* __restrict__ W2_1, const void* __restrict__ W1_1,
    const int* __restrict__ ws, void* __restrict__ outv)
{
  const int bx  = blockIdx.x;
  const int e   = bx >> 7;        // / 128
  const int c   = bx & 127;       // % 128
  const int tid = threadIdx.x;
  const int isbf = ws[15];

  // q = 0: L0;  q = 1..3: L1 m=q-1
  __shared__ float sA3[4*136*16];   // [q][pair][i3], pair-folded U3·W3  (34.8 KB)
  __shared__ float sA2[4*136];      // pair-folded U2·W2
  __shared__ float sA1[4*16];       // U1·W1
  __shared__ unsigned char sI1[136], sI2[136];
  __shared__ float sX[TPB][17];     // per-thread x (stride 17: conflict-free)

  // pair index tables: p -> (i1 <= i2)   [strided: 136 > TPB]
  for (int p = tid; p < 136; p += TPB){
    int i1 = 0, rem = p;
    while (rem >= 16 - i1){ rem -= 16 - i1; i1++; }
    sI1[p] = (unsigned char)i1;
    sI2[p] = (unsigned char)(i1 + rem);
  }

  // per-(e,c) path weights (block-uniform)
  float w3_0[5], w2_0[2], w3_1[7], w2_1[3];
  #pragma unroll
  for (int k = 0; k < 5; k++) w3_0[k] = ld(W3_0, (e*5 + k)*128 + c, isbf);
  #pragma unroll
  for (int k = 0; k < 2; k++) w2_0[k] = ld(W2_0, (e*2 + k)*128 + c, isbf);
  const float w1_0 = ld(W1_0, e*128 + c, isbf);
  #pragma unroll
  for (int k = 0; k < 7; k++) w3_1[k] = ld(W3_1, (e*7 + k)*128 + c, isbf);
  #pragma unroll
  for (int k = 0; k < 3; k++) w2_1[k] = ld(W2_1, (e*3 + k)*128 + c, isbf);
  const float w1_1 = ld(W1_1, e*128 + c, isbf);

  __syncthreads();

  // ---- folded A3:  A3[q][p][i3] = sum_k (U3[i1,i2,i3,k] + [i1<i2] U3[i2,i1,i3,k]) * w ----
  for (int q = 0; q < 4; q++){
    for (int idx = tid; idx < 136*16; idx += TPB){
      const int p  = idx >> 4;
      const int i3 = idx & 15;
      const int i1 = sI1[p], i2 = sI2[p];
      float v = 0.f;
      if (q == 0){
        const int a  = (i1*256 + i2*16 + i3)*5;
        const int bb = (i2*256 + i1*16 + i3)*5;
        #pragma unroll
        for (int k = 0; k < 5; k++){
          float u = ld(U3_0, a + k, isbf);
          if (i1 != i2) u += ld(U3_0, bb + k, isbf);
          v += u * w3_0[k];
        }
      } else {
        const int m  = q - 1;
        const int a  = (m*4096 + i1*256 + i2*16 + i3)*7;
        const int bb = (m*4096 + i2*256 + i1*16 + i3)*7;
        #pragma unroll
        for (int k = 0; k < 7; k++){
          float u = ld(U3_1, a + k, isbf);
          if (i1 != i2) u += ld(U3_1, bb + k, isbf);
          v += u * w3_1[k];
        }
      }
      sA3[q*2176 + idx] = v;
    }
  }
  // ---- folded A2 ----
  for (int idx = tid; idx < 4*136; idx += TPB){
    const int q = idx / 136, p = idx - q*136;
    const int i1 = sI1[p], i2 = sI2[p];
    float v = 0.f;
    if (q == 0){
      const int a = (i1*16 + i2)*2, bb = (i2*16 + i1)*2;
      #pragma unroll
      for (int k = 0; k < 2; k++){
        float u = ld(U2_0, a + k, isbf);
        if (i1 != i2) u += ld(U2_0, bb + k, isbf);
        v += u * w2_0[k];
      }
    } else {
      const int m = q - 1;
      const int a = (m*256 + i1*16 + i2)*3, bb = (m*256 + i2*16 + i1)*3;
      #pragma unroll
      for (int k = 0; k < 3; k++){
        float u = ld(U2_1, a + k, isbf);
        if (i1 != i2) u += ld(U2_1, bb + k, isbf);
        v += u * w2_1[k];
      }
    }
    sA2[idx] = v;
  }
  // ---- A1 ----
  if (tid < 64){
    const int q = tid >> 4, i1 = tid & 15;
    sA1[tid] = (q == 0) ? ld(U1_0, i1, isbf) * w1_0
                        : ld(U1_1, (q - 1)*16 + i1, isbf) * w1_1;
  }
  __syncthreads();

  // ---- atom loop: one atom per thread ----
  const int count = ws[e];
  const int* lst  = ws + 16 + e*1024;

  for (int t = tid; t < count; t += TPB){
    const int b = lst[t];
    const int base = (b*128 + c)*16;

    float xr[16];
    if (isbf){
      const u16* xp = (const u16*)a_i + base;
      u16x8 v0 = *(const u16x8*)(xp);
      u16x8 v1 = *(const u16x8*)(xp + 8);
      #pragma unroll
      for (int i = 0; i < 8; i++){ xr[i] = bf2f(v0[i]); xr[8 + i] = bf2f(v1[i]); }
    } else {
      const float* xp = (const float*)a_i + base;
      f32x4 v0 = *(const f32x4*)(xp);
      f32x4 v1 = *(const f32x4*)(xp + 4);
      f32x4 v2 = *(const f32x4*)(xp + 8);
      f32x4 v3 = *(const f32x4*)(xp + 12);
      #pragma unroll
      for (int i = 0; i < 4; i++){
        xr[i] = v0[i]; xr[4+i] = v1[i]; xr[8+i] = v2[i]; xr[12+i] = v3[i];
      }
    }
    #pragma unroll
    for (int i = 0; i < 16; i++) sX[tid][i] = xr[i];

    float r0 = 0.f, r1 = 0.f, r2 = 0.f, r3 = 0.f;
    int p = 0;
    for (int i1 = 0; i1 < 16; i1++){
      const float x1 = sX[tid][i1];
      for (int i2 = i1; i2 < 16; i2++, p++){
        const float* a0 = &sA3[(0*136 + p)*16];
        const float* a1 = &sA3[(1*136 + p)*16];
        const float* a2 = &sA3[(2*136 + p)*16];
        const float* a3 = &sA3[(3*136 + p)*16];
        float s0 = sA2[        p];
        float s1 = sA2[136   + p];
        float s2 = sA2[272   + p];
        float s3 = sA2[408   + p];
        #pragma unroll
        for (int i3 = 0; i3 < 16; i3++){
          const float xv = xr[i3];
          s0 += a0[i3]*xv;
          s1 += a1[i3]*xv;
          s2 += a2[i3]*xv;
          s3 += a3[i3]*xv;
        }
        const float xx = x1 * sX[tid][i2];
        r0 += s0*xx; r1 += s1*xx; r2 += s2*xx; r3 += s3*xx;
      }
    }
    #pragma unroll
    for (int i1 = 0; i1 < 16; i1++){
      const float xv = xr[i1];
      r0 += sA1[     i1]*xv;
      r1 += sA1[16 + i1]*xv;
      r2 += sA1[32 + i1]*xv;
      r3 += sA1[48 + i1]*xv;
    }

    if (isbf){
      u16* ob = (u16*)outv + (size_t)b*512;
      ob[c]             = f2bf(r0);
      ob[128 + c*3 + 0] = f2bf(r1);
      ob[128 + c*3 + 1] = f2bf(r2);
      ob[128 + c*3 + 2] = f2bf(r3);
    } else {
      float* ob = (float*)outv + (size_t)b*512;
      ob[c]             = r0;
      ob[128 + c*3 + 0] = r1;
      ob[128 + c*3 + 1] = r2;
      ob[128 + c*3 + 2] = r3;
    }
  }
}

extern "C" void kernel_launch(void* const* d_in, const int* in_sizes, int n_in,
                              void* d_out, int out_size, void* d_ws, size_t ws_size,
                              hipStream_t stream) {
  int* ws = (int*)d_ws;
  hipLaunchKernelGGL(k_classify, dim3(1), dim3(1024), 0, stream, d_in[1], ws);
  hipLaunchKernelGGL(k_contract, dim3(1280), dim3(TPB), 0, stream,
                     d_in[0],
                     d_in[2], d_in[3], d_in[4], d_in[5], d_in[6], d_in[7],
                     d_in[8], d_in[9], d_in[10], d_in[11], d_in[12], d_in[13],
                     ws, d_out);
}

// Round 4
// 287.974 us; speedup vs baseline: 1.0893x; 1.0893x over previous
//
#include <hip/hip_runtime.h>
#include <hip/hip_bf16.h>

typedef unsigned short u16;
typedef __attribute__((ext_vector_type(8))) unsigned short u16x8;
typedef __attribute__((ext_vector_type(4))) float f32x4;

#define TPB 128
// ws layout: ints ws[0..9]=counts, ws[15]=isbf16, ws[16+e*1024+j]=atom lists.
// Tables (fast path) at byte offset 65536: per (e,c) slot of 9312 floats:
//   A3 [q][p][i3] at +0 (8704), A2 [q][p] at +8704 (544), A1 [q][i] at +9248 (64)
#define TBL_OFF 65536
#define SLOT 9312
#define WS_NEEDED (TBL_OFF + (size_t)1280 * SLOT * 4)

__device__ __forceinline__ float bf2f(u16 v){
  union { unsigned int u; float f; } x; x.u = ((unsigned int)v) << 16; return x.f;
}
__device__ __forceinline__ u16 f2bf(float f){
  union { float f; unsigned int u; } x; x.f = f;
  unsigned int u = x.u;
  u += 0x7FFFu + ((u >> 16) & 1u);   // round-to-nearest-even
  return (u16)(u >> 16);
}
__device__ __forceinline__ float ld(const void* p, int idx, int isbf){
  return isbf ? bf2f(((const u16*)p)[idx]) : ((const float*)p)[idx];
}

// ---------------- kernel 1: dtype detect + per-species atom lists ------------
__global__ void k_classify(const void* __restrict__ nav, int* __restrict__ ws){
  __shared__ int se[1024];
  __shared__ int sf[16];
  __shared__ int sflag;
  const int b = threadIdx.x;  // 1024 threads

  const unsigned int* w = (const unsigned int*)nav;
  int found = 0;
  for (int i = b; i < 5120; i += 1024) found |= (w[i] == 0x00003F80u);
  unsigned long long m = __ballot(found);
  if ((b & 63) == 0) sf[b >> 6] = (m != 0ULL);
  __syncthreads();
  if (b == 0){ int f = 0; for (int i = 0; i < 16; i++) f |= sf[i]; sflag = f; ws[15] = f; }
  __syncthreads();
  const int isbf = sflag;

  int e = 0;
  #pragma unroll
  for (int j = 0; j < 10; j++){
    if (ld(nav, b*10 + j, isbf) > 0.5f) e = j;
  }
  se[b] = e;
  __syncthreads();
  if (b < 10){
    int cnt = 0;
    int* lst = ws + 16 + b*1024;
    for (int i = 0; i < 1024; i++){
      if (se[i] == b) lst[cnt++] = i;
    }
    ws[b] = cnt;
  }
}

// ---------------- kernel B: build all per-(e,c) tables into ws ---------------
// grid: x = 37*32 (jtile*ctile), y = 40 (e*4+q); block 256 = (4 c) x (64 j)
__global__ __launch_bounds__(256) void k_build(
    const void* __restrict__ U3_0, const void* __restrict__ U2_0, const void* __restrict__ U1_0,
    const void* __restrict__ W3_0, const void* __restrict__ W2_0, const void* __restrict__ W1_0,
    const void* __restrict__ U3_1, const void* __restrict__ U2_1, const void* __restrict__ U1_1,
    const void* __restrict__ W3_1, const void* __restrict__ W2_1, const void* __restrict__ W1_1,
    const int* __restrict__ ws, float* __restrict__ tb)
{
  const int eq = blockIdx.y;
  const int e  = eq >> 2, q = eq & 3;
  const int bx = blockIdx.x;
  const int jt = bx >> 5, ct = bx & 31;
  const int j  = jt*64 + (threadIdx.x & 63);
  const int c  = ct*4 + (threadIdx.x >> 6);
  const int isbf = ws[15];
  if (j >= 2328) return;

  float* base = tb + (size_t)(e*128 + c)*SLOT;

  if (j < 2176){
    const int p = j >> 4, i3 = j & 15;
    int i1 = 0, rem = p;
    while (rem >= 16 - i1){ rem -= 16 - i1; i1++; }
    const int i2 = i1 + rem;
    float v = 0.f;
    if (q == 0){
      const int a  = (i1*256 + i2*16 + i3)*5;
      const int bb = (i2*256 + i1*16 + i3)*5;
      #pragma unroll
      for (int k = 0; k < 5; k++){
        float u = ld(U3_0, a + k, isbf);
        if (i1 != i2) u += ld(U3_0, bb + k, isbf);
        v += u * ld(W3_0, (e*5 + k)*128 + c, isbf);
      }
    } else {
      const int m  = q - 1;
      const int a  = (m*4096 + i1*256 + i2*16 + i3)*7;
      const int bb = (m*4096 + i2*256 + i1*16 + i3)*7;
      #pragma unroll
      for (int k = 0; k < 7; k++){
        float u = ld(U3_1, a + k, isbf);
        if (i1 != i2) u += ld(U3_1, bb + k, isbf);
        v += u * ld(W3_1, (e*7 + k)*128 + c, isbf);
      }
    }
    base[q*2176 + j] = v;
  } else if (j < 2312){
    const int p = j - 2176;
    int i1 = 0, rem = p;
    while (rem >= 16 - i1){ rem -= 16 - i1; i1++; }
    const int i2 = i1 + rem;
    float v = 0.f;
    if (q == 0){
      const int a = (i1*16 + i2)*2, bb = (i2*16 + i1)*2;
      #pragma unroll
      for (int k = 0; k < 2; k++){
        float u = ld(U2_0, a + k, isbf);
        if (i1 != i2) u += ld(U2_0, bb + k, isbf);
        v += u * ld(W2_0, (e*2 + k)*128 + c, isbf);
      }
    } else {
      const int m = q - 1;
      const int a = (m*256 + i1*16 + i2)*3, bb = (m*256 + i2*16 + i1)*3;
      #pragma unroll
      for (int k = 0; k < 3; k++){
        float u = ld(U2_1, a + k, isbf);
        if (i1 != i2) u += ld(U2_1, bb + k, isbf);
        v += u * ld(W2_1, (e*3 + k)*128 + c, isbf);
      }
    }
    base[8704 + q*136 + p] = v;
  } else {
    const int i = j - 2312;
    float v = (q == 0) ? ld(U1_0, i, isbf) * ld(W1_0, e*128 + c, isbf)
                       : ld(U1_1, (q - 1)*16 + i, isbf) * ld(W1_1, e*128 + c, isbf);
    base[9248 + q*16 + i] = v;
  }
}

// ---------------- kernel C: contract, tables via scalar loads ----------------
__global__ __launch_bounds__(TPB) void k_contract2(
    const void* __restrict__ a_i, const int* __restrict__ ws,
    const float* __restrict__ tb, void* __restrict__ outv)
{
  const int e   = blockIdx.x >> 7;
  const int c   = blockIdx.x & 127;
  const int tid = threadIdx.x;
  const int isbf  = ws[15];
  const int count = ws[e];
  const int* lst  = ws + 16 + e*1024;
  const float* __restrict__ base = tb + (size_t)(e*128 + c)*SLOT;

  __shared__ float sX[TPB][17];  // dynamically-indexed private x (stride 17: conflict-free)

  for (int t0 = 0; t0 < count; t0 += TPB){
    int t = t0 + tid;
    const bool act = t < count;
    if (!act) t = count - 1;          // clamp: keep wave converged, discard result
    const int b = lst[t];
    const int xbase = (b*128 + c)*16;

    float xr[16];
    if (isbf){
      const u16* xp = (const u16*)a_i + xbase;
      u16x8 v0 = *(const u16x8*)(xp);
      u16x8 v1 = *(const u16x8*)(xp + 8);
      #pragma unroll
      for (int i = 0; i < 8; i++){ xr[i] = bf2f(v0[i]); xr[8 + i] = bf2f(v1[i]); }
    } else {
      const float* xp = (const float*)a_i + xbase;
      f32x4 v0 = *(const f32x4*)(xp);
      f32x4 v1 = *(const f32x4*)(xp + 4);
      f32x4 v2 = *(const f32x4*)(xp + 8);
      f32x4 v3 = *(const f32x4*)(xp + 12);
      #pragma unroll
      for (int i = 0; i < 4; i++){
        xr[i] = v0[i]; xr[4+i] = v1[i]; xr[8+i] = v2[i]; xr[12+i] = v3[i];
      }
    }
    #pragma unroll
    for (int i = 0; i < 16; i++) sX[tid][i] = xr[i];

    float r0 = 0.f, r1 = 0.f, r2 = 0.f, r3 = 0.f;
    const float* pA3 = base;          // +16 per pair (uniform -> SGPR stream)
    const float* pA2 = base + 8704;   // +1 per pair

    #pragma clang loop unroll(disable)
    for (int i1 = 0; i1 < 16; ++i1){
      const float x1 = sX[tid][i1];
      #pragma clang loop unroll(disable)
      for (int i2 = i1; i2 < 16; ++i2){
        const float xx = x1 * sX[tid][i2];
        float s0 = pA2[0], s1 = pA2[136], s2 = pA2[272], s3 = pA2[408];
        #pragma unroll
        for (int i3 = 0; i3 < 16; ++i3){
          const float xv = xr[i3];
          s0 += pA3[        i3]*xv;
          s1 += pA3[2176 + i3]*xv;
          s2 += pA3[4352 + i3]*xv;
          s3 += pA3[6528 + i3]*xv;
        }
        r0 += s0*xx; r1 += s1*xx; r2 += s2*xx; r3 += s3*xx;
        pA3 += 16; pA2 += 1;
      }
    }
    #pragma unroll
    for (int i = 0; i < 16; i++){
      const float xv = xr[i];
      r0 += base[9248 + i]*xv;
      r1 += base[9264 + i]*xv;
      r2 += base[9280 + i]*xv;
      r3 += base[9296 + i]*xv;
    }

    if (act){
      if (isbf){
        u16* ob = (u16*)outv + (size_t)b*512;
        ob[c]             = f2bf(r0);
        ob[128 + c*3 + 0] = f2bf(r1);
        ob[128 + c*3 + 1] = f2bf(r2);
        ob[128 + c*3 + 2] = f2bf(r3);
      } else {
        float* ob = (float*)outv + (size_t)b*512;
        ob[c]             = r0;
        ob[128 + c*3 + 0] = r1;
        ob[128 + c*3 + 1] = r2;
        ob[128 + c*3 + 2] = r3;
      }
    }
  }
}

// ---------------- fallback (round-3, known-passing): LDS tables --------------
__global__ __launch_bounds__(TPB) void k_contract(
    const void* __restrict__ a_i,
    const void* __restrict__ U3_0, const void* __restrict__ U2_0, const void* __restrict__ U1_0,
    const void* __restrict__ W3_0, const void* __restrict__ W2_0, const void* __restrict__ W1_0,
    const void* __restrict__ U3_1, const void* __restrict__ U2_1, const void* __restrict__ U1_1,
    const void* __restrict__ W3_1, const void* __restrict__ W2_1, const void* __restrict__ W1_1,
    const int* __restrict__ ws, void* __restrict__ outv)
{
  const int bx  = blockIdx.x;
  const int e   = bx >> 7;
  const int c   = bx & 127;
  const int tid = threadIdx.x;
  const int isbf = ws[15];

  __shared__ float sA3[4*136*16];
  __shared__ float sA2[4*136];
  __shared__ float sA1[4*16];
  __shared__ unsigned char sI1[136], sI2[136];
  __shared__ float sX[TPB][17];

  for (int p = tid; p < 136; p += TPB){
    int i1 = 0, rem = p;
    while (rem >= 16 - i1){ rem -= 16 - i1; i1++; }
    sI1[p] = (unsigned char)i1;
    sI2[p] = (unsigned char)(i1 + rem);
  }

  float w3_0[5], w2_0[2], w3_1[7], w2_1[3];
  #pragma unroll
  for (int k = 0; k < 5; k++) w3_0[k] = ld(W3_0, (e*5 + k)*128 + c, isbf);
  #pragma unroll
  for (int k = 0; k < 2; k++) w2_0[k] = ld(W2_0, (e*2 + k)*128 + c, isbf);
  const float w1_0 = ld(W1_0, e*128 + c, isbf);
  #pragma unroll
  for (int k = 0; k < 7; k++) w3_1[k] = ld(W3_1, (e*7 + k)*128 + c, isbf);
  #pragma unroll
  for (int k = 0; k < 3; k++) w2_1[k] = ld(W2_1, (e*3 + k)*128 + c, isbf);
  const float w1_1 = ld(W1_1, e*128 + c, isbf);

  __syncthreads();

  for (int q = 0; q < 4; q++){
    for (int idx = tid; idx < 136*16; idx += TPB){
      const int p  = idx >> 4;
      const int i3 = idx & 15;
      const int i1 = sI1[p], i2 = sI2[p];
      float v = 0.f;
      if (q == 0){
        const int a  = (i1*256 + i2*16 + i3)*5;
        const int bb = (i2*256 + i1*16 + i3)*5;
        #pragma unroll
        for (int k = 0; k < 5; k++){
          float u = ld(U3_0, a + k, isbf);
          if (i1 != i2) u += ld(U3_0, bb + k, isbf);
          v += u * w3_0[k];
        }
      } else {
        const int m  = q - 1;
        const int a  = (m*4096 + i1*256 + i2*16 + i3)*7;
        const int bb = (m*4096 + i2*256 + i1*16 + i3)*7;
        #pragma unroll
        for (int k = 0; k < 7; k++){
          float u = ld(U3_1, a + k, isbf);
          if (i1 != i2) u += ld(U3_1, bb + k, isbf);
          v += u * w3_1[k];
        }
      }
      sA3[q*2176 + idx] = v;
    }
  }
  for (int idx = tid; idx < 4*136; idx += TPB){
    const int q = idx / 136, p = idx - q*136;
    const int i1 = sI1[p], i2 = sI2[p];
    float v = 0.f;
    if (q == 0){
      const int a = (i1*16 + i2)*2, bb = (i2*16 + i1)*2;
      #pragma unroll
      for (int k = 0; k < 2; k++){
        float u = ld(U2_0, a + k, isbf);
        if (i1 != i2) u += ld(U2_0, bb + k, isbf);
        v += u * w2_0[k];
      }
    } else {
      const int m = q - 1;
      const int a = (m*256 + i1*16 + i2)*3, bb = (m*256 + i2*16 + i1)*3;
      #pragma unroll
      for (int k = 0; k < 3; k++){
        float u = ld(U2_1, a + k, isbf);
        if (i1 != i2) u += ld(U2_1, bb + k, isbf);
        v += u * w2_1[k];
      }
    }
    sA2[idx] = v;
  }
  if (tid < 64){
    const int q = tid >> 4, i1 = tid & 15;
    sA1[tid] = (q == 0) ? ld(U1_0, i1, isbf) * w1_0
                        : ld(U1_1, (q - 1)*16 + i1, isbf) * w1_1;
  }
  __syncthreads();

  const int count = ws[e];
  const int* lst  = ws + 16 + e*1024;

  for (int t = tid; t < count; t += TPB){
    const int b = lst[t];
    const int xbase = (b*128 + c)*16;

    float xr[16];
    if (isbf){
      const u16* xp = (const u16*)a_i + xbase;
      u16x8 v0 = *(const u16x8*)(xp);
      u16x8 v1 = *(const u16x8*)(xp + 8);
      #pragma unroll
      for (int i = 0; i < 8; i++){ xr[i] = bf2f(v0[i]); xr[8 + i] = bf2f(v1[i]); }
    } else {
      const float* xp = (const float*)a_i + xbase;
      f32x4 v0 = *(const f32x4*)(xp);
      f32x4 v1 = *(const f32x4*)(xp + 4);
      f32x4 v2 = *(const f32x4*)(xp + 8);
      f32x4 v3 = *(const f32x4*)(xp + 12);
      #pragma unroll
      for (int i = 0; i < 4; i++){
        xr[i] = v0[i]; xr[4+i] = v1[i]; xr[8+i] = v2[i]; xr[12+i] = v3[i];
      }
    }
    #pragma unroll
    for (int i = 0; i < 16; i++) sX[tid][i] = xr[i];

    float r0 = 0.f, r1 = 0.f, r2 = 0.f, r3 = 0.f;
    int p = 0;
    for (int i1 = 0; i1 < 16; i1++){
      const float x1 = sX[tid][i1];
      for (int i2 = i1; i2 < 16; i2++, p++){
        const float* a0 = &sA3[(0*136 + p)*16];
        const float* a1 = &sA3[(1*136 + p)*16];
        const float* a2 = &sA3[(2*136 + p)*16];
        const float* a3 = &sA3[(3*136 + p)*16];
        float s0 = sA2[        p];
        float s1 = sA2[136   + p];
        float s2 = sA2[272   + p];
        float s3 = sA2[408   + p];
        #pragma unroll
        for (int i3 = 0; i3 < 16; i3++){
          const float xv = xr[i3];
          s0 += a0[i3]*xv;
          s1 += a1[i3]*xv;
          s2 += a2[i3]*xv;
          s3 += a3[i3]*xv;
        }
        const float xx = x1 * sX[tid][i2];
        r0 += s0*xx; r1 += s1*xx; r2 += s2*xx; r3 += s3*xx;
      }
    }
    #pragma unroll
    for (int i1 = 0; i1 < 16; i1++){
      const float xv = xr[i1];
      r0 += sA1[     i1]*xv;
      r1 += sA1[16 + i1]*xv;
      r2 += sA1[32 + i1]*xv;
      r3 += sA1[48 + i1]*xv;
    }

    if (isbf){
      u16* ob = (u16*)outv + (size_t)b*512;
      ob[c]             = f2bf(r0);
      ob[128 + c*3 + 0] = f2bf(r1);
      ob[128 + c*3 + 1] = f2bf(r2);
      ob[128 + c*3 + 2] = f2bf(r3);
    } else {
      float* ob = (float*)outv + (size_t)b*512;
      ob[c]             = r0;
      ob[128 + c*3 + 0] = r1;
      ob[128 + c*3 + 1] = r2;
      ob[128 + c*3 + 2] = r3;
    }
  }
}

extern "C" void kernel_launch(void* const* d_in, const int* in_sizes, int n_in,
                              void* d_out, int out_size, void* d_ws, size_t ws_size,
                              hipStream_t stream) {
  int* ws = (int*)d_ws;
  hipLaunchKernelGGL(k_classify, dim3(1), dim3(1024), 0, stream, d_in[1], ws);

  if (ws_size >= WS_NEEDED){
    float* tb = (float*)((char*)d_ws + TBL_OFF);
    hipLaunchKernelGGL(k_build, dim3(37*32, 40), dim3(256), 0, stream,
                       d_in[2], d_in[3], d_in[4], d_in[5], d_in[6], d_in[7],
                       d_in[8], d_in[9], d_in[10], d_in[11], d_in[12], d_in[13],
                       ws, tb);
    hipLaunchKernelGGL(k_contract2, dim3(1280), dim3(TPB), 0, stream,
                       d_in[0], ws, tb, d_out);
  } else {
    hipLaunchKernelGGL(k_contract, dim3(1280), dim3(TPB), 0, stream,
                       d_in[0],
                       d_in[2], d_in[3], d_in[4], d_in[5], d_in[6], d_in[7],
                       d_in[8], d_in[9], d_in[10], d_in[11], d_in[12], d_in[13],
                       ws, d_out);
  }
}

// Round 5
// 140.922 us; speedup vs baseline: 2.2260x; 2.0435x over previous
//
#include <hip/hip_runtime.h>
#include <hip/hip_bf16.h>

typedef unsigned short u16;
typedef __attribute__((ext_vector_type(8))) unsigned short u16x8;
typedef __attribute__((ext_vector_type(4))) float f32x4;

#define TPB 128
// ws layout: ints ws[0..9]=counts, ws[15]=isbf16, ws[16+e*1024+j]=atom lists.
// Tables at byte 65536: per (e,c) slot of 9312 floats:
//   A3 [q][p][i3] at +0 (8704), A2 [q][p] at +8704 (544), A1 [q][i] at +9248 (64)
#define TBL_OFF 65536
#define SLOT 9312
#define TBL_BYTES ((size_t)1280 * SLOT * 4)
#define PART_OFF (TBL_OFF + TBL_BYTES)
#define PART_BYTES ((size_t)4 * 1024 * 512 * 4)
#define WS_NEEDED_OLD (TBL_OFF + TBL_BYTES)
#define WS_NEEDED_NEW (PART_OFF + PART_BYTES)

__device__ __forceinline__ float bf2f(u16 v){
  union { unsigned int u; float f; } x; x.u = ((unsigned int)v) << 16; return x.f;
}
__device__ __forceinline__ u16 f2bf(float f){
  union { float f; unsigned int u; } x; x.f = f;
  unsigned int u = x.u;
  u += 0x7FFFu + ((u >> 16) & 1u);   // round-to-nearest-even
  return (u16)(u >> 16);
}
__device__ __forceinline__ float ld(const void* p, int idx, int isbf){
  return isbf ? bf2f(((const u16*)p)[idx]) : ((const float*)p)[idx];
}

// ============ kernel 1 (new): dtype detect + parallel species lists ==========
__global__ void k_classify2(const void* __restrict__ nav, int* __restrict__ ws){
  __shared__ int scnt[10];
  __shared__ int sf[16];
  __shared__ int sflag;
  const int b = threadIdx.x;  // 1024 threads
  if (b < 10) scnt[b] = 0;

  // dtype detection: bf16 one-hot at even index -> word 0x00003F80 (never valid f32 here)
  const unsigned int* w = (const unsigned int*)nav;
  int found = 0;
  for (int i = b; i < 5120; i += 1024) found |= (w[i] == 0x00003F80u);
  unsigned long long m = __ballot(found);
  if ((b & 63) == 0) sf[b >> 6] = (m != 0ULL);
  __syncthreads();
  if (b == 0){ int f = 0; for (int i = 0; i < 16; i++) f |= sf[i]; sflag = f; ws[15] = f; }
  __syncthreads();
  const int isbf = sflag;

  int e = 0;
  #pragma unroll
  for (int j = 0; j < 10; j++){
    if (ld(nav, b*10 + j, isbf) > 0.5f) e = j;
  }
  // list order is irrelevant: per-atom outputs are order-independent
  int pos = atomicAdd(&scnt[e], 1);
  ws[16 + e*1024 + pos] = b;
  __syncthreads();
  if (b < 10) ws[b] = scnt[b];
}

// ============ kernel B (new): build tables; thread=j, 8 c serial =============
// grid (73 jtiles, 16 cgroups, 10 e), block 128
__global__ __launch_bounds__(128) void k_build2(
    const void* __restrict__ U3_0, const void* __restrict__ U2_0, const void* __restrict__ U1_0,
    const void* __restrict__ W3_0, const void* __restrict__ W2_0, const void* __restrict__ W1_0,
    const void* __restrict__ U3_1, const void* __restrict__ U2_1, const void* __restrict__ U1_1,
    const void* __restrict__ W3_1, const void* __restrict__ W2_1, const void* __restrict__ W1_1,
    const int* __restrict__ ws, float* __restrict__ tb)
{
  const int jt = blockIdx.x, cg = blockIdx.y, e = blockIdx.z;
  const int j  = jt*128 + threadIdx.x;
  const int isbf = ws[15];
  if (j >= 9312) return;
  const int c0 = cg*8;

  float u[7];
  int K, wbase, dst;
  const void* Wp;

  if (j < 8704){
    const int q = j / 2176, rem = j % 2176;
    const int p = rem >> 4, i3 = rem & 15;
    int i1 = 0, rr = p;
    while (rr >= 16 - i1){ rr -= 16 - i1; i1++; }
    const int i2 = i1 + rr;
    if (q == 0){
      K = 5; Wp = W3_0; wbase = e*5;
      const int a  = (i1*256 + i2*16 + i3)*5;
      const int bb = (i2*256 + i1*16 + i3)*5;
      #pragma unroll
      for (int k = 0; k < 5; k++){
        float v = ld(U3_0, a + k, isbf);
        if (i1 != i2) v += ld(U3_0, bb + k, isbf);
        u[k] = v;
      }
    } else {
      K = 7; Wp = W3_1; wbase = e*7;
      const int mm = q - 1;
      const int a  = (mm*4096 + i1*256 + i2*16 + i3)*7;
      const int bb = (mm*4096 + i2*256 + i1*16 + i3)*7;
      #pragma unroll
      for (int k = 0; k < 7; k++){
        float v = ld(U3_1, a + k, isbf);
        if (i1 != i2) v += ld(U3_1, bb + k, isbf);
        u[k] = v;
      }
    }
    dst = j;
  } else if (j < 9248){
    const int jj = j - 8704;            // 0..543
    const int q = jj / 136, p = jj % 136;
    int i1 = 0, rr = p;
    while (rr >= 16 - i1){ rr -= 16 - i1; i1++; }
    const int i2 = i1 + rr;
    if (q == 0){
      K = 2; Wp = W2_0; wbase = e*2;
      const int a = (i1*16 + i2)*2, bb = (i2*16 + i1)*2;
      #pragma unroll
      for (int k = 0; k < 2; k++){
        float v = ld(U2_0, a + k, isbf);
        if (i1 != i2) v += ld(U2_0, bb + k, isbf);
        u[k] = v;
      }
    } else {
      K = 3; Wp = W2_1; wbase = e*3;
      const int mm = q - 1;
      const int a = (mm*256 + i1*16 + i2)*3, bb = (mm*256 + i2*16 + i1)*3;
      #pragma unroll
      for (int k = 0; k < 3; k++){
        float v = ld(U2_1, a + k, isbf);
        if (i1 != i2) v += ld(U2_1, bb + k, isbf);
        u[k] = v;
      }
    }
    dst = 8704 + jj;
  } else {
    const int jj = j - 9248;            // 0..63
    const int q = jj >> 4, i = jj & 15;
    K = 1;
    if (q == 0){ Wp = W1_0; wbase = e; u[0] = ld(U1_0, i, isbf); }
    else       { Wp = W1_1; wbase = e; u[0] = ld(U1_1, (q - 1)*16 + i, isbf); }
    dst = 9248 + jj;
  }

  for (int cc = 0; cc < 8; cc++){
    const int c = c0 + cc;
    float v = 0.f;
    for (int k = 0; k < K; k++) v += u[k] * ld(Wp, (wbase + k)*128 + c, isbf);
    tb[(size_t)(e*128 + c)*SLOT + dst] = v;
  }
}

// ============ kernel C (new): contract, pair-chunked (PC=4 x 34 pairs) =======
// grid (1280, 4); partials to part[pc][b][c*4+q]
__global__ __launch_bounds__(TPB) void k_contract3(
    const void* __restrict__ a_i, const int* __restrict__ ws,
    const float* __restrict__ tb, float* __restrict__ part)
{
  const int e   = blockIdx.x >> 7;
  const int c   = blockIdx.x & 127;
  const int pc  = blockIdx.y;
  const int tid = threadIdx.x;
  const int isbf  = ws[15];
  const int count = ws[e];
  const int* lst  = ws + 16 + e*1024;
  const float* __restrict__ base = tb + (size_t)(e*128 + c)*SLOT;
  if (count == 0) return;

  __shared__ float sX[TPB][17];
  const int p0 = pc*34;

  for (int t0 = 0; t0 < count; t0 += TPB){
    int t = t0 + tid;
    const bool act = t < count;
    if (!act) t = count - 1;          // clamp: same value recomputed, benign
    const int b = lst[t];
    const int xbase = (b*128 + c)*16;

    float xr[16];
    if (isbf){
      const u16* xp = (const u16*)a_i + xbase;
      u16x8 v0 = *(const u16x8*)(xp);
      u16x8 v1 = *(const u16x8*)(xp + 8);
      #pragma unroll
      for (int i = 0; i < 8; i++){ xr[i] = bf2f(v0[i]); xr[8 + i] = bf2f(v1[i]); }
    } else {
      const float* xp = (const float*)a_i + xbase;
      f32x4 v0 = *(const f32x4*)(xp);
      f32x4 v1 = *(const f32x4*)(xp + 4);
      f32x4 v2 = *(const f32x4*)(xp + 8);
      f32x4 v3 = *(const f32x4*)(xp + 12);
      #pragma unroll
      for (int i = 0; i < 4; i++){
        xr[i] = v0[i]; xr[4+i] = v1[i]; xr[8+i] = v2[i]; xr[12+i] = v3[i];
      }
    }
    #pragma unroll
    for (int i = 0; i < 16; i++) sX[tid][i] = xr[i];

    float r0 = 0.f, r1 = 0.f, r2 = 0.f, r3 = 0.f;
    const float* pA3 = base + p0*16;
    const float* pA2 = base + 8704 + p0;
    int i1 = 0, rm = p0;
    while (rm >= 16 - i1){ rm -= 16 - i1; i1++; }
    int i2 = i1 + rm;

    #pragma clang loop unroll(disable)
    for (int n = 0; n < 34; ++n){
      const float xx = sX[tid][i1] * sX[tid][i2];
      float s0 = pA2[0], s1 = pA2[136], s2 = pA2[272], s3 = pA2[408];
      #pragma unroll
      for (int i3 = 0; i3 < 16; ++i3){
        const float xv = xr[i3];
        s0 += pA3[        i3]*xv;
        s1 += pA3[2176 + i3]*xv;
        s2 += pA3[4352 + i3]*xv;
        s3 += pA3[6528 + i3]*xv;
      }
      r0 += s0*xx; r1 += s1*xx; r2 += s2*xx; r3 += s3*xx;
      pA3 += 16; pA2 += 1;
      i2++; if (i2 == 16){ i1++; i2 = i1; }
    }

    if (pc == 3){
      #pragma unroll
      for (int i = 0; i < 16; i++){
        const float xv = xr[i];
        r0 += base[9248 + i]*xv;
        r1 += base[9264 + i]*xv;
        r2 += base[9280 + i]*xv;
        r3 += base[9296 + i]*xv;
      }
    }

    if (act){
      f32x4 v; v[0] = r0; v[1] = r1; v[2] = r2; v[3] = r3;
      *(f32x4*)(part + ((size_t)(pc*1024 + b)*512 + c*4)) = v;
    }
  }
}

// ============ kernel D (new): combine partials + convert =====================
__global__ __launch_bounds__(128) void k_combine(
    const float* __restrict__ part, const int* __restrict__ ws, void* __restrict__ outv)
{
  const int b = blockIdx.x, c = threadIdx.x;
  const int isbf = ws[15];
  f32x4 r;
  r[0] = 0.f; r[1] = 0.f; r[2] = 0.f; r[3] = 0.f;
  #pragma unroll
  for (int pc = 0; pc < 4; pc++){
    f32x4 v = *(const f32x4*)(part + ((size_t)(pc*1024 + b)*512 + c*4));
    r[0] += v[0]; r[1] += v[1]; r[2] += v[2]; r[3] += v[3];
  }
  if (isbf){
    u16* ob = (u16*)outv + (size_t)b*512;
    ob[c]             = f2bf(r[0]);
    ob[128 + c*3 + 0] = f2bf(r[1]);
    ob[128 + c*3 + 1] = f2bf(r[2]);
    ob[128 + c*3 + 2] = f2bf(r[3]);
  } else {
    float* ob = (float*)outv + (size_t)b*512;
    ob[c]             = r[0];
    ob[128 + c*3 + 0] = r[1];
    ob[128 + c*3 + 1] = r[2];
    ob[128 + c*3 + 2] = r[3];
  }
}

// ===================== fallback kernels (rounds 3/4, verified) ===============
__global__ __launch_bounds__(256) void k_build(
    const void* __restrict__ U3_0, const void* __restrict__ U2_0, const void* __restrict__ U1_0,
    const void* __restrict__ W3_0, const void* __restrict__ W2_0, const void* __restrict__ W1_0,
    const void* __restrict__ U3_1, const void* __restrict__ U2_1, const void* __restrict__ U1_1,
    const void* __restrict__ W3_1, const void* __restrict__ W2_1, const void* __restrict__ W1_1,
    const int* __restrict__ ws, float* __restrict__ tb)
{
  const int eq = blockIdx.y;
  const int e  = eq >> 2, q = eq & 3;
  const int bx = blockIdx.x;
  const int jt = bx >> 5, ct = bx & 31;
  const int j  = jt*64 + (threadIdx.x & 63);
  const int c  = ct*4 + (threadIdx.x >> 6);
  const int isbf = ws[15];
  if (j >= 2328) return;

  float* base = tb + (size_t)(e*128 + c)*SLOT;

  if (j < 2176){
    const int p = j >> 4, i3 = j & 15;
    int i1 = 0, rem = p;
    while (rem >= 16 - i1){ rem -= 16 - i1; i1++; }
    const int i2 = i1 + rem;
    float v = 0.f;
    if (q == 0){
      const int a  = (i1*256 + i2*16 + i3)*5;
      const int bb = (i2*256 + i1*16 + i3)*5;
      #pragma unroll
      for (int k = 0; k < 5; k++){
        float u = ld(U3_0, a + k, isbf);
        if (i1 != i2) u += ld(U3_0, bb + k, isbf);
        v += u * ld(W3_0, (e*5 + k)*128 + c, isbf);
      }
    } else {
      const int m  = q - 1;
      const int a  = (m*4096 + i1*256 + i2*16 + i3)*7;
      const int bb = (m*4096 + i2*256 + i1*16 + i3)*7;
      #pragma unroll
      for (int k = 0; k < 7; k++){
        float u = ld(U3_1, a + k, isbf);
        if (i1 != i2) u += ld(U3_1, bb + k, isbf);
        v += u * ld(W3_1, (e*7 + k)*128 + c, isbf);
      }
    }
    base[q*2176 + j] = v;
  } else if (j < 2312){
    const int p = j - 2176;
    int i1 = 0, rem = p;
    while (rem >= 16 - i1){ rem -= 16 - i1; i1++; }
    const int i2 = i1 + rem;
    float v = 0.f;
    if (q == 0){
      const int a = (i1*16 + i2)*2, bb = (i2*16 + i1)*2;
      #pragma unroll
      for (int k = 0; k < 2; k++){
        float u = ld(U2_0, a + k, isbf);
        if (i1 != i2) u += ld(U2_0, bb + k, isbf);
        v += u * ld(W2_0, (e*2 + k)*128 + c, isbf);
      }
    } else {
      const int m = q - 1;
      const int a = (m*256 + i1*16 + i2)*3, bb = (m*256 + i2*16 + i1)*3;
      #pragma unroll
      for (int k = 0; k < 3; k++){
        float u = ld(U2_1, a + k, isbf);
        if (i1 != i2) u += ld(U2_1, bb + k, isbf);
        v += u * ld(W2_1, (e*3 + k)*128 + c, isbf);
      }
    }
    base[8704 + q*136 + p] = v;
  } else {
    const int i = j - 2312;
    float v = (q == 0) ? ld(U1_0, i, isbf) * ld(W1_0, e*128 + c, isbf)
                       : ld(U1_1, (q - 1)*16 + i, isbf) * ld(W1_1, e*128 + c, isbf);
    base[9248 + q*16 + i] = v;
  }
}

__global__ __launch_bounds__(TPB) void k_contract2(
    const void* __restrict__ a_i, const int* __restrict__ ws,
    const float* __restrict__ tb, void* __restrict__ outv)
{
  const int e   = blockIdx.x >> 7;
  const int c   = blockIdx.x & 127;
  const int tid = threadIdx.x;
  const int isbf  = ws[15];
  const int count = ws[e];
  const int* lst  = ws + 16 + e*1024;
  const float* __restrict__ base = tb + (size_t)(e*128 + c)*SLOT;

  __shared__ float sX[TPB][17];

  for (int t0 = 0; t0 < count; t0 += TPB){
    int t = t0 + tid;
    const bool act = t < count;
    if (!act) t = count - 1;
    const int b = lst[t];
    const int xbase = (b*128 + c)*16;

    float xr[16];
    if (isbf){
      const u16* xp = (const u16*)a_i + xbase;
      u16x8 v0 = *(const u16x8*)(xp);
      u16x8 v1 = *(const u16x8*)(xp + 8);
      #pragma unroll
      for (int i = 0; i < 8; i++){ xr[i] = bf2f(v0[i]); xr[8 + i] = bf2f(v1[i]); }
    } else {
      const float* xp = (const float*)a_i + xbase;
      f32x4 v0 = *(const f32x4*)(xp);
      f32x4 v1 = *(const f32x4*)(xp + 4);
      f32x4 v2 = *(const f32x4*)(xp + 8);
      f32x4 v3 = *(const f32x4*)(xp + 12);
      #pragma unroll
      for (int i = 0; i < 4; i++){
        xr[i] = v0[i]; xr[4+i] = v1[i]; xr[8+i] = v2[i]; xr[12+i] = v3[i];
      }
    }
    #pragma unroll
    for (int i = 0; i < 16; i++) sX[tid][i] = xr[i];

    float r0 = 0.f, r1 = 0.f, r2 = 0.f, r3 = 0.f;
    const float* pA3 = base;
    const float* pA2 = base + 8704;

    #pragma clang loop unroll(disable)
    for (int i1 = 0; i1 < 16; ++i1){
      const float x1 = sX[tid][i1];
      #pragma clang loop unroll(disable)
      for (int i2 = i1; i2 < 16; ++i2){
        const float xx = x1 * sX[tid][i2];
        float s0 = pA2[0], s1 = pA2[136], s2 = pA2[272], s3 = pA2[408];
        #pragma unroll
        for (int i3 = 0; i3 < 16; ++i3){
          const float xv = xr[i3];
          s0 += pA3[        i3]*xv;
          s1 += pA3[2176 + i3]*xv;
          s2 += pA3[4352 + i3]*xv;
          s3 += pA3[6528 + i3]*xv;
        }
        r0 += s0*xx; r1 += s1*xx; r2 += s2*xx; r3 += s3*xx;
        pA3 += 16; pA2 += 1;
      }
    }
    #pragma unroll
    for (int i = 0; i < 16; i++){
      const float xv = xr[i];
      r0 += base[9248 + i]*xv;
      r1 += base[9264 + i]*xv;
      r2 += base[9280 + i]*xv;
      r3 += base[9296 + i]*xv;
    }

    if (act){
      if (isbf){
        u16* ob = (u16*)outv + (size_t)b*512;
        ob[c]             = f2bf(r0);
        ob[128 + c*3 + 0] = f2bf(r1);
        ob[128 + c*3 + 1] = f2bf(r2);
        ob[128 + c*3 + 2] = f2bf(r3);
      } else {
        float* ob = (float*)outv + (size_t)b*512;
        ob[c]             = r0;
        ob[128 + c*3 + 0] = r1;
        ob[128 + c*3 + 1] = r2;
        ob[128 + c*3 + 2] = r3;
      }
    }
  }
}

__global__ __launch_bounds__(TPB) void k_contract(
    const void* __restrict__ a_i,
    const void* __restrict__ U3_0, const void* __restrict__ U2_0, const void* __restrict__ U1_0,
    const void* __restrict__ W3_0, const void* __restrict__ W2_0, const void* __restrict__ W1_0,
    const void* __restrict__ U3_1, const void* __restrict__ U2_1, const void* __restrict__ U1_1,
    const void* __restrict__ W3_1, const void* __restrict__ W2_1, const void* __restrict__ W1_1,
    const int* __restrict__ ws, void* __restrict__ outv)
{
  const int bx  = blockIdx.x;
  const int e   = bx >> 7;
  const int c   = bx & 127;
  const int tid = threadIdx.x;
  const int isbf = ws[15];

  __shared__ float sA3[4*136*16];
  __shared__ float sA2[4*136];
  __shared__ float sA1[4*16];
  __shared__ unsigned char sI1[136], sI2[136];
  __shared__ float sX[TPB][17];

  for (int p = tid; p < 136; p += TPB){
    int i1 = 0, rem = p;
    while (rem >= 16 - i1){ rem -= 16 - i1; i1++; }
    sI1[p] = (unsigned char)i1;
    sI2[p] = (unsigned char)(i1 + rem);
  }

  float w3_0[5], w2_0[2], w3_1[7], w2_1[3];
  #pragma unroll
  for (int k = 0; k < 5; k++) w3_0[k] = ld(W3_0, (e*5 + k)*128 + c, isbf);
  #pragma unroll
  for (int k = 0; k < 2; k++) w2_0[k] = ld(W2_0, (e*2 + k)*128 + c, isbf);
  const float w1_0 = ld(W1_0, e*128 + c, isbf);
  #pragma unroll
  for (int k = 0; k < 7; k++) w3_1[k] = ld(W3_1, (e*7 + k)*128 + c, isbf);
  #pragma unroll
  for (int k = 0; k < 3; k++) w2_1[k] = ld(W2_1, (e*3 + k)*128 + c, isbf);
  const float w1_1 = ld(W1_1, e*128 + c, isbf);

  __syncthreads();

  for (int q = 0; q < 4; q++){
    for (int idx = tid; idx < 136*16; idx += TPB){
      const int p  = idx >> 4;
      const int i3 = idx & 15;
      const int i1 = sI1[p], i2 = sI2[p];
      float v = 0.f;
      if (q == 0){
        const int a  = (i1*256 + i2*16 + i3)*5;
        const int bb = (i2*256 + i1*16 + i3)*5;
        #pragma unroll
        for (int k = 0; k < 5; k++){
          float u = ld(U3_0, a + k, isbf);
          if (i1 != i2) u += ld(U3_0, bb + k, isbf);
          v += u * w3_0[k];
        }
      } else {
        const int m  = q - 1;
        const int a  = (m*4096 + i1*256 + i2*16 + i3)*7;
        const int bb = (m*4096 + i2*256 + i1*16 + i3)*7;
        #pragma unroll
        for (int k = 0; k < 7; k++){
          float u = ld(U3_1, a + k, isbf);
          if (i1 != i2) u += ld(U3_1, bb + k, isbf);
          v += u * w3_1[k];
        }
      }
      sA3[q*2176 + idx] = v;
    }
  }
  for (int idx = tid; idx < 4*136; idx += TPB){
    const int q = idx / 136, p = idx - q*136;
    const int i1 = sI1[p], i2 = sI2[p];
    float v = 0.f;
    if (q == 0){
      const int a = (i1*16 + i2)*2, bb = (i2*16 + i1)*2;
      #pragma unroll
      for (int k = 0; k < 2; k++){
        float u = ld(U2_0, a + k, isbf);
        if (i1 != i2) u += ld(U2_0, bb + k, isbf);
        v += u * w2_0[k];
      }
    } else {
      const int m = q - 1;
      const int a = (m*256 + i1*16 + i2)*3, bb = (m*256 + i2*16 + i1)*3;
      #pragma unroll
      for (int k = 0; k < 3; k++){
        float u = ld(U2_1, a + k, isbf);
        if (i1 != i2) u += ld(U2_1, bb + k, isbf);
        v += u * w2_1[k];
      }
    }
    sA2[idx] = v;
  }
  if (tid < 64){
    const int q = tid >> 4, i1 = tid & 15;
    sA1[tid] = (q == 0) ? ld(U1_0, i1, isbf) * w1_0
                        : ld(U1_1, (q - 1)*16 + i1, isbf) * w1_1;
  }
  __syncthreads();

  const int count = ws[e];
  const int* lst  = ws + 16 + e*1024;

  for (int t = tid; t < count; t += TPB){
    const int b = lst[t];
    const int xbase = (b*128 + c)*16;

    float xr[16];
    if (isbf){
      const u16* xp = (const u16*)a_i + xbase;
      u16x8 v0 = *(const u16x8*)(xp);
      u16x8 v1 = *(const u16x8*)(xp + 8);
      #pragma unroll
      for (int i = 0; i < 8; i++){ xr[i] = bf2f(v0[i]); xr[8 + i] = bf2f(v1[i]); }
    } else {
      const float* xp = (const float*)a_i + xbase;
      f32x4 v0 = *(const f32x4*)(xp);
      f32x4 v1 = *(const f32x4*)(xp + 4);
      f32x4 v2 = *(const f32x4*)(xp + 8);
      f32x4 v3 = *(const f32x4*)(xp + 12);
      #pragma unroll
      for (int i = 0; i < 4; i++){
        xr[i] = v0[i]; xr[4+i] = v1[i]; xr[8+i] = v2[i]; xr[12+i] = v3[i];
      }
    }
    #pragma unroll
    for (int i = 0; i < 16; i++) sX[tid][i] = xr[i];

    float r0 = 0.f, r1 = 0.f, r2 = 0.f, r3 = 0.f;
    int p = 0;
    for (int i1 = 0; i1 < 16; i1++){
      const float x1 = sX[tid][i1];
      for (int i2 = i1; i2 < 16; i2++, p++){
        const float* a0 = &sA3[(0*136 + p)*16];
        const float* a1 = &sA3[(1*136 + p)*16];
        const float* a2 = &sA3[(2*136 + p)*16];
        const float* a3 = &sA3[(3*136 + p)*16];
        float s0 = sA2[        p];
        float s1 = sA2[136   + p];
        float s2 = sA2[272   + p];
        float s3 = sA2[408   + p];
        #pragma unroll
        for (int i3 = 0; i3 < 16; i3++){
          const float xv = xr[i3];
          s0 += a0[i3]*xv;
          s1 += a1[i3]*xv;
          s2 += a2[i3]*xv;
          s3 += a3[i3]*xv;
        }
        const float xx = x1 * sX[tid][i2];
        r0 += s0*xx; r1 += s1*xx; r2 += s2*xx; r3 += s3*xx;
      }
    }
    #pragma unroll
    for (int i1 = 0; i1 < 16; i1++){
      const float xv = xr[i1];
      r0 += sA1[     i1]*xv;
      r1 += sA1[16 + i1]*xv;
      r2 += sA1[32 + i1]*xv;
      r3 += sA1[48 + i1]*xv;
    }

    if (isbf){
      u16* ob = (u16*)outv + (size_t)b*512;
      ob[c]             = f2bf(r0);
      ob[128 + c*3 + 0] = f2bf(r1);
      ob[128 + c*3 + 1] = f2bf(r2);
      ob[128 + c*3 + 2] = f2bf(r3);
    } else {
      float* ob = (float*)outv + (size_t)b*512;
      ob[c]             = r0;
      ob[128 + c*3 + 0] = r1;
      ob[128 + c*3 + 1] = r2;
      ob[128 + c*3 + 2] = r3;
    }
  }
}

extern "C" void kernel_launch(void* const* d_in, const int* in_sizes, int n_in,
                              void* d_out, int out_size, void* d_ws, size_t ws_size,
                              hipStream_t stream) {
  int* ws = (int*)d_ws;
  hipLaunchKernelGGL(k_classify2, dim3(1), dim3(1024), 0, stream, d_in[1], ws);

  if (ws_size >= WS_NEEDED_NEW){
    float* tb   = (float*)((char*)d_ws + TBL_OFF);
    float* part = (float*)((char*)d_ws + PART_OFF);
    hipLaunchKernelGGL(k_build2, dim3(73, 16, 10), dim3(128), 0, stream,
                       d_in[2], d_in[3], d_in[4], d_in[5], d_in[6], d_in[7],
                       d_in[8], d_in[9], d_in[10], d_in[11], d_in[12], d_in[13],
                       ws, tb);
    hipLaunchKernelGGL(k_contract3, dim3(1280, 4), dim3(TPB), 0, stream,
                       d_in[0], ws, tb, part);
    hipLaunchKernelGGL(k_combine, dim3(1024), dim3(128), 0, stream,
                       part, ws, d_out);
  } else if (ws_size >= WS_NEEDED_OLD){
    float* tb = (float*)((char*)d_ws + TBL_OFF);
    hipLaunchKernelGGL(k_build, dim3(37*32, 40), dim3(256), 0, stream,
                       d_in[2], d_in[3], d_in[4], d_in[5], d_in[6], d_in[7],
                       d_in[8], d_in[9], d_in[10], d_in[11], d_in[12], d_in[13],
                       ws, tb);
    hipLaunchKernelGGL(k_contract2, dim3(1280), dim3(TPB), 0, stream,
                       d_in[0], ws, tb, d_out);
  } else {
    hipLaunchKernelGGL(k_contract, dim3(1280), dim3(TPB), 0, stream,
                       d_in[0],
                       d_in[2], d_in[3], d_in[4], d_in[5], d_in[6], d_in[7],
                       d_in[8], d_in[9], d_in[10], d_in[11], d_in[12], d_in[13],
                       ws, d_out);
  }
}